// Round 2
// baseline (160.048 us; speedup 1.0000x reference)
//
#include <hip/hip_runtime.h>
#include <hip/hip_bf16.h>

// BiClassifier B=4 N=128 D=768 HID=1024 OUT=2
// k1 prepack: Abig[1024][2304] bf16 = [hi|lo|hi] of stacked inputs
//             Wbig[2][1024][2304] bf16 = [hi|hi|lo] of W1, W2
// k2 gemm_mfma: hid[1024][1024] fp32 = Abig @ Wbig[sel].T (K'=2304 折 3-term split)
// k3 pair: out[b,n,m,o] = sum_h relu(hid[bn][h]+hid[512+bm][h])*Wo[o][h] + bo[o]

typedef __attribute__((ext_vector_type(8))) short s16x8;
typedef __attribute__((ext_vector_type(4))) float f32x4;

#define KP 2304
#define BK 64

__global__ __launch_bounds__(256) void prepack(
    const float* __restrict__ in1, const float* __restrict__ in2,
    const float* __restrict__ W1, const float* __restrict__ W2,
    ushort* __restrict__ Abig, ushort* __restrict__ Wbig)
{
    const int gid = blockIdx.x * 256 + threadIdx.x;   // 589824 total
    const int src = gid / 196608;                     // 0:A 1:W1 2:W2
    const int rem = gid % 196608;
    const int row = rem / 192;
    const int k4  = (rem % 192) * 4;
    const float* sp;
    ushort* dst;
    if (src == 0) {
        sp  = (row < 512) ? in1 + (size_t)row * 768 + k4
                          : in2 + (size_t)(row - 512) * 768 + k4;
        dst = Abig + (size_t)row * KP + k4;
    } else {
        sp  = (src == 1 ? W1 : W2) + (size_t)row * 768 + k4;
        dst = Wbig + (size_t)(src - 1) * (1024 * KP) + (size_t)row * KP + k4;
    }
    const float4 x = *(const float4*)sp;
    const float xf[4] = {x.x, x.y, x.z, x.w};
    ushort h[4], l[4];
    #pragma unroll
    for (int i = 0; i < 4; ++i) {
        const float v = xf[i];
        __hip_bfloat16 bh = __float2bfloat16(v);
        const float fh = __bfloat162float(bh);
        __hip_bfloat16 bl = __float2bfloat16(v - fh);
        h[i] = *(ushort*)&bh;
        l[i] = *(ushort*)&bl;
    }
    const ushort4 H = make_ushort4(h[0], h[1], h[2], h[3]);
    const ushort4 L = make_ushort4(l[0], l[1], l[2], l[3]);
    if (src == 0) {   // A: [hi | lo | hi]
        *(ushort4*)(dst)        = H;
        *(ushort4*)(dst + 768)  = L;
        *(ushort4*)(dst + 1536) = H;
    } else {          // W: [hi | hi | lo]
        *(ushort4*)(dst)        = H;
        *(ushort4*)(dst + 768)  = H;
        *(ushort4*)(dst + 1536) = L;
    }
}

// 64x64 tile per block, 4 waves (2x2), wave tile 32x32 = 2x2 frags of 16x16x32
__global__ __launch_bounds__(256) void gemm_mfma(
    const ushort* __restrict__ Abig, const ushort* __restrict__ Wbig,
    const float* __restrict__ b1, float* __restrict__ hid)
{
    const int t    = threadIdx.x;
    const int lane = t & 63;
    const int w    = t >> 6;
    const int row0 = blockIdx.y * 64;
    const int col0 = blockIdx.x * 64;
    const ushort* __restrict__ A = Abig + (size_t)row0 * KP;
    const ushort* __restrict__ W = Wbig + (row0 < 512 ? (size_t)0 : (size_t)1024 * KP)
                                   + (size_t)col0 * KP;

    __shared__ ushort lds[2][64 * BK];   // [0]=A tile, [1]=W tile; XOR-swizzled phys layout

    // staging: thread t owns phys bytes [t*32, t*32+32) of each tile (row = t>>2)
    const int srow = t >> 2;
    int kb[2];
    #pragma unroll
    for (int j = 0; j < 2; ++j)
        kb[j] = (((t & 3) * 32 + j * 16) ^ ((srow & 7) << 4));  // logical k-byte in row

    // fragment read offsets (phys = logical ^ ((row&7)<<4); row&7 == lane&7 here)
    const int wr = w >> 1, wc = w & 1;
    const int l15 = lane & 15, kg = lane >> 4;
    int aoff[2][2], boff[2][2];   // [kk][frag]
    #pragma unroll
    for (int kk = 0; kk < 2; ++kk)
        #pragma unroll
        for (int f = 0; f < 2; ++f) {
            const int r = wr * 32 + f * 16 + l15;
            const int c = wc * 32 + f * 16 + l15;
            const int sw_ = ((kk * 64 + kg * 16));
            aoff[kk][f] = r * 128 + (sw_ ^ ((r & 7) << 4));
            boff[kk][f] = c * 128 + (sw_ ^ ((c & 7) << 4));
        }

    const f32x4 zero = {0.f, 0.f, 0.f, 0.f};
    f32x4 acc[2][2] = {{zero, zero}, {zero, zero}};

    int4 ra[2], rw[2];
    #pragma unroll
    for (int j = 0; j < 2; ++j) {
        ra[j] = *(const int4*)(A + (size_t)srow * KP + (kb[j] >> 1));
        rw[j] = *(const int4*)(W + (size_t)srow * KP + (kb[j] >> 1));
    }

    for (int kt = 0; kt < KP / BK; ++kt) {
        __syncthreads();
        #pragma unroll
        for (int j = 0; j < 2; ++j) {
            *(int4*)((char*)&lds[0][0] + t * 32 + j * 16) = ra[j];
            *(int4*)((char*)&lds[1][0] + t * 32 + j * 16) = rw[j];
        }
        __syncthreads();
        if (kt + 1 < KP / BK) {
            const int k0 = (kt + 1) * BK;
            #pragma unroll
            for (int j = 0; j < 2; ++j) {
                ra[j] = *(const int4*)(A + (size_t)srow * KP + k0 + (kb[j] >> 1));
                rw[j] = *(const int4*)(W + (size_t)srow * KP + k0 + (kb[j] >> 1));
            }
        }
        #pragma unroll
        for (int kk = 0; kk < 2; ++kk) {
            s16x8 af[2], bf_[2];
            #pragma unroll
            for (int f = 0; f < 2; ++f) {
                af[f]  = *(const s16x8*)((const char*)&lds[0][0] + aoff[kk][f]);
                bf_[f] = *(const s16x8*)((const char*)&lds[1][0] + boff[kk][f]);
            }
            #pragma unroll
            for (int fr = 0; fr < 2; ++fr)
                #pragma unroll
                for (int fc = 0; fc < 2; ++fc)
                    acc[fr][fc] = __builtin_amdgcn_mfma_f32_16x16x32_bf16(
                        af[fr], bf_[fc], acc[fr][fc], 0, 0, 0);
        }
    }

    // C/D layout: col = lane&15, row = (lane>>4)*4 + i   [m89-verified]
    float bias[2] = {0.f, 0.f};
    if (row0 < 512) {
        bias[0] = b1[col0 + wc * 32 + l15];
        bias[1] = b1[col0 + wc * 32 + 16 + l15];
    }
    #pragma unroll
    for (int fr = 0; fr < 2; ++fr)
        #pragma unroll
        for (int fc = 0; fc < 2; ++fc)
            #pragma unroll
            for (int i = 0; i < 4; ++i) {
                const int r = row0 + wr * 32 + fr * 16 + kg * 4 + i;
                const int c = col0 + wc * 32 + fc * 16 + l15;
                hid[(size_t)r * 1024 + c] = acc[fr][fc][i] + bias[fc];
            }
}

#define HC 128

__global__ __launch_bounds__(256) void pair_kernel(
    const float* __restrict__ hid, const float* __restrict__ Wo,
    const float* __restrict__ bo, float* __restrict__ out)
{
    const int t  = threadIdx.x;
    const int b  = blockIdx.z;
    const int n0 = blockIdx.y * 16;
    const int m0 = blockIdx.x * 16;
    const float* __restrict__ in1 = hid + ((size_t)b * 128 + n0) * 1024;
    const float* __restrict__ in2 = hid + (size_t)512 * 1024 + ((size_t)b * 128 + m0) * 1024;

    __shared__ float s1[16][132];
    __shared__ float s2[16][132];
    __shared__ float sw[2][1024];   // all of Wo, loaded once

    #pragma unroll
    for (int q = 0; q < 2; ++q) {
        const int idx = q * 256 + t;          // float4 index 0..511
        *(float4*)&((float*)sw)[idx * 4] = *(const float4*)&Wo[idx * 4];
    }

    const int sr = t >> 5;
    const int sc = (t & 31) << 2;

    float4 a0 = *(const float4*)(in1 + (size_t)sr * 1024 + sc);
    float4 a1 = *(const float4*)(in1 + (size_t)(sr + 8) * 1024 + sc);
    float4 c0 = *(const float4*)(in2 + (size_t)sr * 1024 + sc);
    float4 c1 = *(const float4*)(in2 + (size_t)(sr + 8) * 1024 + sc);

    const int i = t >> 4;
    const int j = t & 15;
    float acc0 = 0.f, acc1 = 0.f;

    for (int hc = 0; hc < 1024 / HC; ++hc) {
        __syncthreads();
        *(float4*)&s1[sr][sc] = a0;
        *(float4*)&s1[sr + 8][sc] = a1;
        *(float4*)&s2[sr][sc] = c0;
        *(float4*)&s2[sr + 8][sc] = c1;
        __syncthreads();
        if (hc < 1024 / HC - 1) {
            const int off = (hc + 1) * HC;
            a0 = *(const float4*)(in1 + (size_t)sr * 1024 + off + sc);
            a1 = *(const float4*)(in1 + (size_t)(sr + 8) * 1024 + off + sc);
            c0 = *(const float4*)(in2 + (size_t)sr * 1024 + off + sc);
            c1 = *(const float4*)(in2 + (size_t)(sr + 8) * 1024 + off + sc);
        }
        const float* swp0 = &sw[0][hc * HC];
        const float* swp1 = &sw[1][hc * HC];
        #pragma unroll
        for (int hh = 0; hh < HC; hh += 4) {
            const float4 x = *(const float4*)&s1[i][hh];
            const float4 y = *(const float4*)&s2[j][hh];
            const float4 u = *(const float4*)&swp0[hh];
            const float4 v = *(const float4*)&swp1[hh];
            float r;
            r = fmaxf(x.x + y.x, 0.f); acc0 = fmaf(r, u.x, acc0); acc1 = fmaf(r, v.x, acc1);
            r = fmaxf(x.y + y.y, 0.f); acc0 = fmaf(r, u.y, acc0); acc1 = fmaf(r, v.y, acc1);
            r = fmaxf(x.z + y.z, 0.f); acc0 = fmaf(r, u.z, acc0); acc1 = fmaf(r, v.z, acc1);
            r = fmaxf(x.w + y.w, 0.f); acc0 = fmaf(r, u.w, acc0); acc1 = fmaf(r, v.w, acc1);
        }
    }

    const float2 ob = *(const float2*)bo;
    const size_t o = (((size_t)b * 128 + n0 + i) * 128 + (m0 + j)) * 2;
    out[o]     = acc0 + ob.x;
    out[o + 1] = acc1 + ob.y;
}

extern "C" void kernel_launch(void* const* d_in, const int* in_sizes, int n_in,
                              void* d_out, int out_size, void* d_ws, size_t ws_size,
                              hipStream_t stream) {
    (void)in_sizes; (void)n_in; (void)out_size; (void)ws_size;
    const float* input1 = (const float*)d_in[0];
    const float* input2 = (const float*)d_in[1];
    const float* W1     = (const float*)d_in[2];
    const float* b1     = (const float*)d_in[3];
    const float* W2     = (const float*)d_in[4];
    const float* Wo     = (const float*)d_in[5];
    const float* bo     = (const float*)d_in[6];
    float* out = (float*)d_out;

    ushort* Abig = (ushort*)d_ws;                       // 1024*2304*2B = 4.72 MB
    ushort* Wbig = Abig + (size_t)1024 * KP;            // 2*1024*2304*2B = 9.44 MB
    float*  hid  = (float*)(Wbig + (size_t)2 * 1024 * KP);  // 4 MB

    prepack<<<2304, 256, 0, stream>>>(input1, input2, W1, W2, Abig, Wbig);
    gemm_mfma<<<dim3(16, 16), 256, 0, stream>>>(Abig, Wbig, b1, hid);
    pair_kernel<<<dim3(8, 8, 4), 256, 0, stream>>>(hid, Wo, bo, out);
}

// Round 3
// 146.131 us; speedup vs baseline: 1.0952x; 1.0952x over previous
//
#include <hip/hip_runtime.h>
#include <hip/hip_bf16.h>

// BiClassifier B=4 N=128 D=768 HID=1024 OUT=2
// k0 hid_init: hid[r][c] = (r<512 ? b1[c] : 0)
// k1 prepack:  Abig[1024][2304] bf16 = [hi|lo|hi] of stacked inputs
//              Wbig[2][1024][2304] bf16 = [hi|hi|lo] of W1, W2
// k2 gemm_mfma: hid += Abig @ Wbig[sel].T  (split-K x4, atomicAdd epilogue)
// k3 pair: out[b,n,m,o] = sum_h relu(hid[bn][h]+hid[512+bm][h])*Wo[o][h] + bo[o]

typedef __attribute__((ext_vector_type(8))) short s16x8;
typedef __attribute__((ext_vector_type(4))) float f32x4;

#define KP 2304
#define BK 64
#define KSPLIT 4
#define KRANGE 576   // KP / KSPLIT

__device__ __forceinline__ void gl_lds16(const void* g, void* l) {
    __builtin_amdgcn_global_load_lds(
        (const __attribute__((address_space(1))) unsigned int*)g,
        (__attribute__((address_space(3))) unsigned int*)l, 16, 0, 0);
}

__global__ __launch_bounds__(256) void hid_init(
    const float* __restrict__ b1, float* __restrict__ hid)
{
    const int g   = blockIdx.x * 256 + threadIdx.x;   // 262144 float4s
    const int row = g >> 8;
    const int c4  = (g & 255) << 2;
    float4 v = make_float4(0.f, 0.f, 0.f, 0.f);
    if (row < 512) v = *(const float4*)&b1[c4];
    *(float4*)&hid[(size_t)row * 1024 + c4] = v;
}

__global__ __launch_bounds__(256) void prepack(
    const float* __restrict__ in1, const float* __restrict__ in2,
    const float* __restrict__ W1, const float* __restrict__ W2,
    ushort* __restrict__ Abig, ushort* __restrict__ Wbig)
{
    const int gid = blockIdx.x * 256 + threadIdx.x;   // 589824 total
    const int src = gid / 196608;                     // 0:A 1:W1 2:W2
    const int rem = gid % 196608;
    const int row = rem / 192;
    const int k4  = (rem % 192) * 4;
    const float* sp;
    ushort* dst;
    if (src == 0) {
        sp  = (row < 512) ? in1 + (size_t)row * 768 + k4
                          : in2 + (size_t)(row - 512) * 768 + k4;
        dst = Abig + (size_t)row * KP + k4;
    } else {
        sp  = (src == 1 ? W1 : W2) + (size_t)row * 768 + k4;
        dst = Wbig + (size_t)(src - 1) * (1024 * KP) + (size_t)row * KP + k4;
    }
    const float4 x = *(const float4*)sp;
    const float xf[4] = {x.x, x.y, x.z, x.w};
    ushort h[4], l[4];
    #pragma unroll
    for (int i = 0; i < 4; ++i) {
        const float v = xf[i];
        __hip_bfloat16 bh = __float2bfloat16(v);
        const float fh = __bfloat162float(bh);
        __hip_bfloat16 bl = __float2bfloat16(v - fh);
        h[i] = *(ushort*)&bh;
        l[i] = *(ushort*)&bl;
    }
    const ushort4 H = make_ushort4(h[0], h[1], h[2], h[3]);
    const ushort4 L = make_ushort4(l[0], l[1], l[2], l[3]);
    if (src == 0) {   // A: [hi | lo | hi]
        *(ushort4*)(dst)        = H;
        *(ushort4*)(dst + 768)  = L;
        *(ushort4*)(dst + 1536) = H;
    } else {          // W: [hi | hi | lo]
        *(ushort4*)(dst)        = H;
        *(ushort4*)(dst + 768)  = H;
        *(ushort4*)(dst + 1536) = L;
    }
}

// 64x64 tile, 4 waves (2x2), wave tile 32x32 = 2x2 frags of 16x16x32 bf16.
// Split-K x4 across blockIdx.z; global_load_lds staging (pre-swizzled global
// source + linear LDS dest), double-buffered, 1 barrier per K-step.
__global__ __launch_bounds__(256) void gemm_mfma(
    const ushort* __restrict__ Abig, const ushort* __restrict__ Wbig,
    float* __restrict__ hid)
{
    const int t    = threadIdx.x;
    const int lane = t & 63;
    const int w    = t >> 6;
    const int row0 = blockIdx.y * 64;
    const int col0 = blockIdx.x * 64;
    const int k0   = blockIdx.z * KRANGE;

    const char* __restrict__ A = (const char*)(Abig + (size_t)row0 * KP + k0);
    const char* __restrict__ W = (const char*)(Wbig
                                   + (row0 < 512 ? (size_t)0 : (size_t)1024 * KP)
                                   + (size_t)col0 * KP + k0);

    __shared__ ushort lds[2][2][4096];   // [buf][A/W][8KB tile]

    // staging geometry: chunk q (0..7) covers LDS bytes [q*1024, q*1024+1024),
    // lane writes 16B at q*1024 + lane*16 (linear dest). Source is the
    // XOR-swizzle-inverse global position so reads can swizzle.
    const int lrow = lane >> 3;                       // row-within-chunk
    const int kbyt = ((lane & 7) ^ lrow) << 4;        // logical k-byte
    const size_t rstrA = (size_t)(lrow) * (KP * 2);   // lane's row byte offset part

    // fragment read offsets: phys = logical ^ ((row&7)<<4)
    const int wr = w >> 1, wc = w & 1;
    const int l15 = lane & 15, kg = lane >> 4;
    int aoff[2][2], boff[2][2];
    #pragma unroll
    for (int kk = 0; kk < 2; ++kk)
        #pragma unroll
        for (int f = 0; f < 2; ++f) {
            const int r = wr * 32 + f * 16 + l15;
            const int c = wc * 32 + f * 16 + l15;
            const int sw_ = kk * 64 + kg * 16;
            aoff[kk][f] = r * 128 + (sw_ ^ ((r & 7) << 4));
            boff[kk][f] = c * 128 + (sw_ ^ ((c & 7) << 4));
        }

#define STAGE(buf, ktk) do {                                                   \
        const size_t kby = (size_t)(ktk) * (BK * 2);                           \
        _Pragma("unroll")                                                      \
        for (int qq = 0; qq < 2; ++qq) {                                       \
            const int q = w * 2 + qq;                                          \
            const size_t roff = (size_t)q * 8 * (KP * 2) + rstrA + kby + kbyt; \
            gl_lds16(A + roff, (char*)&lds[buf][0][0] + q * 1024 + lane * 16); \
            gl_lds16(W + roff, (char*)&lds[buf][1][0] + q * 1024 + lane * 16); \
        }                                                                      \
    } while (0)

    const f32x4 zero = {0.f, 0.f, 0.f, 0.f};
    f32x4 acc[2][2] = {{zero, zero}, {zero, zero}};

    STAGE(0, 0);
    int cur = 0;
    for (int kt = 0; kt < KRANGE / BK; ++kt) {
        asm volatile("s_waitcnt vmcnt(0)" ::: "memory");
        __syncthreads();
        if (kt + 1 < KRANGE / BK) STAGE(cur ^ 1, kt + 1);
        #pragma unroll
        for (int kk = 0; kk < 2; ++kk) {
            s16x8 af[2], bf_[2];
            #pragma unroll
            for (int f = 0; f < 2; ++f) {
                af[f]  = *(const s16x8*)((const char*)&lds[cur][0][0] + aoff[kk][f]);
                bf_[f] = *(const s16x8*)((const char*)&lds[cur][1][0] + boff[kk][f]);
            }
            #pragma unroll
            for (int fr = 0; fr < 2; ++fr)
                #pragma unroll
                for (int fc = 0; fc < 2; ++fc)
                    acc[fr][fc] = __builtin_amdgcn_mfma_f32_16x16x32_bf16(
                        af[fr], bf_[fc], acc[fr][fc], 0, 0, 0);
        }
        cur ^= 1;
    }
#undef STAGE

    // C/D layout: col = lane&15, row = (lane>>4)*4 + i
    #pragma unroll
    for (int fr = 0; fr < 2; ++fr)
        #pragma unroll
        for (int fc = 0; fc < 2; ++fc)
            #pragma unroll
            for (int i = 0; i < 4; ++i) {
                const int r = row0 + wr * 32 + fr * 16 + kg * 4 + i;
                const int c = col0 + wc * 32 + fc * 16 + l15;
                atomicAdd(&hid[(size_t)r * 1024 + c], acc[fr][fc][i]);
            }
}

// 8x8 pair tile, 1024 blocks (4/CU). Wave w owns h-quarter [w*256,w*256+256).
// No in-loop barriers; straight L2 reads; one LDS reduce at the end.
__global__ __launch_bounds__(256, 4) void pair_kernel(
    const float* __restrict__ hid, const float* __restrict__ Wo,
    const float* __restrict__ bo, float* __restrict__ out)
{
    const int t  = threadIdx.x;
    const int b  = blockIdx.z;
    const int n0 = blockIdx.y * 8;
    const int m0 = blockIdx.x * 8;
    const int hs = t >> 6;          // wave index = h quarter
    const int p  = t & 63;
    const int i  = p >> 3, j = p & 7;

    const float* __restrict__ r1 = hid + ((size_t)(b * 128 + n0 + i)) * 1024 + hs * 256;
    const float* __restrict__ r2 = hid + ((size_t)(512 + b * 128 + m0 + j)) * 1024 + hs * 256;
    const float* __restrict__ w0 = Wo + hs * 256;
    const float* __restrict__ w1 = Wo + 1024 + hs * 256;

    float a0 = 0.f, a1 = 0.f;
    #pragma unroll 4
    for (int q = 0; q < 64; ++q) {
        const float4 x = *(const float4*)&r1[q * 4];
        const float4 y = *(const float4*)&r2[q * 4];
        const float4 u = *(const float4*)&w0[q * 4];
        const float4 v = *(const float4*)&w1[q * 4];
        float r;
        r = fmaxf(x.x + y.x, 0.f); a0 = fmaf(r, u.x, a0); a1 = fmaf(r, v.x, a1);
        r = fmaxf(x.y + y.y, 0.f); a0 = fmaf(r, u.y, a0); a1 = fmaf(r, v.y, a1);
        r = fmaxf(x.z + y.z, 0.f); a0 = fmaf(r, u.z, a0); a1 = fmaf(r, v.z, a1);
        r = fmaxf(x.w + y.w, 0.f); a0 = fmaf(r, u.w, a0); a1 = fmaf(r, v.w, a1);
    }

    __shared__ float sred[4][64][2];
    sred[hs][p][0] = a0;
    sred[hs][p][1] = a1;
    __syncthreads();
    if (t < 64) {
        const float s0 = sred[0][t][0] + sred[1][t][0] + sred[2][t][0] + sred[3][t][0];
        const float s1 = sred[0][t][1] + sred[1][t][1] + sred[2][t][1] + sred[3][t][1];
        const float2 ob = *(const float2*)bo;
        const int ii = t >> 3, jj = t & 7;
        const size_t o = (((size_t)b * 128 + n0 + ii) * 128 + (m0 + jj)) * 2;
        *(float2*)&out[o] = make_float2(s0 + ob.x, s1 + ob.y);
    }
}

extern "C" void kernel_launch(void* const* d_in, const int* in_sizes, int n_in,
                              void* d_out, int out_size, void* d_ws, size_t ws_size,
                              hipStream_t stream) {
    (void)in_sizes; (void)n_in; (void)out_size; (void)ws_size;
    const float* input1 = (const float*)d_in[0];
    const float* input2 = (const float*)d_in[1];
    const float* W1     = (const float*)d_in[2];
    const float* b1     = (const float*)d_in[3];
    const float* W2     = (const float*)d_in[4];
    const float* Wo     = (const float*)d_in[5];
    const float* bo     = (const float*)d_in[6];
    float* out = (float*)d_out;

    ushort* Abig = (ushort*)d_ws;                           // 4.72 MB
    ushort* Wbig = Abig + (size_t)1024 * KP;                // 9.44 MB
    float*  hid  = (float*)(Wbig + (size_t)2 * 1024 * KP);  // 4 MB

    hid_init<<<1024, 256, 0, stream>>>(b1, hid);
    prepack<<<2304, 256, 0, stream>>>(input1, input2, W1, W2, Abig, Wbig);
    gemm_mfma<<<dim3(16, 16, KSPLIT), 256, 0, stream>>>(Abig, Wbig, hid);
    pair_kernel<<<dim3(16, 16, 4), 256, 0, stream>>>(hid, Wo, bo, out);
}

// Round 5
// 129.237 us; speedup vs baseline: 1.2384x; 1.1307x over previous
//
#include <hip/hip_runtime.h>
#include <hip/hip_bf16.h>

// BiClassifier B=4 N=128 D=768 HID=1024 OUT=2
// k0 hid_init: hid[r][c] = (r<512 ? b1[c] : 0)                  [R3-proven]
// k1 prepack:  Abig[1024][2304] bf16 = [hi|lo|hi] of stacked inputs
//              Wbig[2][1024][2304] bf16 = [hi|hi|lo] of W1, W2  [R3-proven]
// k2 gemm_mfma: hid += Abig @ Wbig[sel].T (split-K x4, atomicAdd) [R3-proven]
// k3 out_init: out[p][o] = bo[o]
// k4 pair: per (32x32 pair tile, h-range 64): atomicAdd out += relu-bilinear partial

typedef __attribute__((ext_vector_type(8))) short s16x8;
typedef __attribute__((ext_vector_type(4))) float f32x4;

#define KP 2304
#define BK 64
#define KSPLIT 4
#define KRANGE 576   // KP / KSPLIT
#define HSPLIT 16

__device__ __forceinline__ void gl_lds16(const void* g, void* l) {
    __builtin_amdgcn_global_load_lds(
        (const __attribute__((address_space(1))) unsigned int*)g,
        (__attribute__((address_space(3))) unsigned int*)l, 16, 0, 0);
}

__global__ __launch_bounds__(256) void hid_init(
    const float* __restrict__ b1, float* __restrict__ hid)
{
    const int g   = blockIdx.x * 256 + threadIdx.x;   // 262144 float4s
    const int row = g >> 8;
    const int c4  = (g & 255) << 2;
    float4 v = make_float4(0.f, 0.f, 0.f, 0.f);
    if (row < 512) v = *(const float4*)&b1[c4];
    *(float4*)&hid[(size_t)row * 1024 + c4] = v;
}

__global__ __launch_bounds__(256) void prepack(
    const float* __restrict__ in1, const float* __restrict__ in2,
    const float* __restrict__ W1, const float* __restrict__ W2,
    ushort* __restrict__ Abig, ushort* __restrict__ Wbig)
{
    const int gid = blockIdx.x * 256 + threadIdx.x;   // 589824 total
    const int src = gid / 196608;                     // 0:A 1:W1 2:W2
    const int rem = gid % 196608;
    const int row = rem / 192;
    const int k4  = (rem % 192) * 4;
    const float* sp;
    ushort* dst;
    if (src == 0) {
        sp  = (row < 512) ? in1 + (size_t)row * 768 + k4
                          : in2 + (size_t)(row - 512) * 768 + k4;
        dst = Abig + (size_t)row * KP + k4;
    } else {
        sp  = (src == 1 ? W1 : W2) + (size_t)row * 768 + k4;
        dst = Wbig + (size_t)(src - 1) * (1024 * KP) + (size_t)row * KP + k4;
    }
    const float4 x = *(const float4*)sp;
    const float xf[4] = {x.x, x.y, x.z, x.w};
    ushort h[4], l[4];
    #pragma unroll
    for (int i = 0; i < 4; ++i) {
        const float v = xf[i];
        __hip_bfloat16 bh = __float2bfloat16(v);
        const float fh = __bfloat162float(bh);
        __hip_bfloat16 bl = __float2bfloat16(v - fh);
        h[i] = *(ushort*)&bh;
        l[i] = *(ushort*)&bl;
    }
    const ushort4 H = make_ushort4(h[0], h[1], h[2], h[3]);
    const ushort4 L = make_ushort4(l[0], l[1], l[2], l[3]);
    if (src == 0) {   // A: [hi | lo | hi]
        *(ushort4*)(dst)        = H;
        *(ushort4*)(dst + 768)  = L;
        *(ushort4*)(dst + 1536) = H;
    } else {          // W: [hi | hi | lo]
        *(ushort4*)(dst)        = H;
        *(ushort4*)(dst + 768)  = H;
        *(ushort4*)(dst + 1536) = L;
    }
}

// 64x64 tile, 4 waves (2x2), wave tile 32x32 = 2x2 frags of 16x16x32 bf16.
// Split-K x4 across blockIdx.z; atomicAdd epilogue into b1-preloaded hid.
__global__ __launch_bounds__(256) void gemm_mfma(
    const ushort* __restrict__ Abig, const ushort* __restrict__ Wbig,
    float* __restrict__ hid)
{
    const int t    = threadIdx.x;
    const int lane = t & 63;
    const int w    = t >> 6;
    const int row0 = blockIdx.y * 64;
    const int col0 = blockIdx.x * 64;
    const int k0   = blockIdx.z * KRANGE;

    const char* __restrict__ A = (const char*)(Abig + (size_t)row0 * KP + k0);
    const char* __restrict__ W = (const char*)(Wbig
                                   + (row0 < 512 ? (size_t)0 : (size_t)1024 * KP)
                                   + (size_t)col0 * KP + k0);

    __shared__ ushort lds[2][2][4096];   // [buf][A/W][8KB tile]

    const int lrow = lane >> 3;                       // row-within-chunk
    const int kbyt = ((lane & 7) ^ lrow) << 4;        // swizzle-inverse k-byte
    const size_t rstrA = (size_t)(lrow) * (KP * 2);

    const int wr = w >> 1, wc = w & 1;
    const int l15 = lane & 15, kg = lane >> 4;
    int aoff[2][2], boff[2][2];
    #pragma unroll
    for (int kk = 0; kk < 2; ++kk)
        #pragma unroll
        for (int f = 0; f < 2; ++f) {
            const int r = wr * 32 + f * 16 + l15;
            const int c = wc * 32 + f * 16 + l15;
            const int sw_ = kk * 64 + kg * 16;
            aoff[kk][f] = r * 128 + (sw_ ^ ((r & 7) << 4));
            boff[kk][f] = c * 128 + (sw_ ^ ((c & 7) << 4));
        }

#define STAGE(buf, ktk) do {                                                   \
        const size_t kby = (size_t)(ktk) * (BK * 2);                           \
        _Pragma("unroll")                                                      \
        for (int qq = 0; qq < 2; ++qq) {                                       \
            const int q = w * 2 + qq;                                          \
            const size_t roff = (size_t)q * 8 * (KP * 2) + rstrA + kby + kbyt; \
            gl_lds16(A + roff, (char*)&lds[buf][0][0] + q * 1024 + lane * 16); \
            gl_lds16(W + roff, (char*)&lds[buf][1][0] + q * 1024 + lane * 16); \
        }                                                                      \
    } while (0)

    const f32x4 zero = {0.f, 0.f, 0.f, 0.f};
    f32x4 acc[2][2] = {{zero, zero}, {zero, zero}};

    STAGE(0, 0);
    int cur = 0;
    for (int kt = 0; kt < KRANGE / BK; ++kt) {
        asm volatile("s_waitcnt vmcnt(0)" ::: "memory");
        __syncthreads();
        if (kt + 1 < KRANGE / BK) STAGE(cur ^ 1, kt + 1);
        #pragma unroll
        for (int kk = 0; kk < 2; ++kk) {
            s16x8 af[2], bf_[2];
            #pragma unroll
            for (int f = 0; f < 2; ++f) {
                af[f]  = *(const s16x8*)((const char*)&lds[cur][0][0] + aoff[kk][f]);
                bf_[f] = *(const s16x8*)((const char*)&lds[cur][1][0] + boff[kk][f]);
            }
            #pragma unroll
            for (int fr = 0; fr < 2; ++fr)
                #pragma unroll
                for (int fc = 0; fc < 2; ++fc)
                    acc[fr][fc] = __builtin_amdgcn_mfma_f32_16x16x32_bf16(
                        af[fr], bf_[fc], acc[fr][fc], 0, 0, 0);
        }
        cur ^= 1;
    }
#undef STAGE

    // C/D layout: col = lane&15, row = (lane>>4)*4 + i
    #pragma unroll
    for (int fr = 0; fr < 2; ++fr)
        #pragma unroll
        for (int fc = 0; fc < 2; ++fc)
            #pragma unroll
            for (int i = 0; i < 4; ++i) {
                const int r = row0 + wr * 32 + fr * 16 + kg * 4 + i;
                const int c = col0 + wc * 32 + fc * 16 + l15;
                atomicAdd(&hid[(size_t)r * 1024 + c], acc[fr][fc][i]);
            }
}

__global__ __launch_bounds__(256) void out_init(
    const float* __restrict__ bo, float* __restrict__ out)
{
    const int g = blockIdx.x * 256 + threadIdx.x;   // 65536 pairs
    *(float2*)&out[(size_t)g * 2] = make_float2(bo[0], bo[1]);
}

// 32x32 pair tile x h-range 64. Each thread owns a 2x2 pair sub-tile.
// Reads the single summed hid plane; atomicAdd partials onto bo-initialized out.
#define PSTR 68   // LDS row stride (floats)

__global__ __launch_bounds__(256) void pair_kernel(
    const float* __restrict__ hid, const float* __restrict__ Wo,
    float* __restrict__ out)
{
    const int t  = threadIdx.x;
    const int b  = blockIdx.y >> 2;
    const int n0 = (blockIdx.y & 3) * 32;
    const int m0 = blockIdx.x * 32;
    const int h0 = blockIdx.z * 64;

    __shared__ float s1[32][PSTR];
    __shared__ float s2[32][PSTR];
    __shared__ float sw[2][64];

    #pragma unroll
    for (int p = 0; p < 2; ++p) {
        const int idx = p * 256 + t;
        const int r = idx >> 4;
        const int c = (idx & 15) << 2;
        *(float4*)&s1[r][c] =
            *(const float4*)&hid[((size_t)(b * 128 + n0 + r)) * 1024 + h0 + c];
        *(float4*)&s2[r][c] =
            *(const float4*)&hid[((size_t)(512 + b * 128 + m0 + r)) * 1024 + h0 + c];
    }
    if (t < 32) {
        const int o = t >> 4;
        const int c = (t & 15) << 2;
        *(float4*)&sw[o][c] = *(const float4*)&Wo[(size_t)o * 1024 + h0 + c];
    }
    __syncthreads();

    const int ti = t >> 4, tj = t & 15;
    const int i0 = ti * 2, j0 = tj * 2;
    float acc[2][2][2] = {};   // [n][m][o]

    #pragma unroll
    for (int c4 = 0; c4 < 16; ++c4) {
        const int c = c4 << 2;
        const float4 x0 = *(const float4*)&s1[i0][c];
        const float4 x1 = *(const float4*)&s1[i0 + 1][c];
        const float4 y0 = *(const float4*)&s2[j0][c];
        const float4 y1 = *(const float4*)&s2[j0 + 1][c];
        const float4 u  = *(const float4*)&sw[0][c];
        const float4 v  = *(const float4*)&sw[1][c];
        #pragma unroll
        for (int k = 0; k < 4; ++k) {
            const float xk0 = ((const float*)&x0)[k];
            const float xk1 = ((const float*)&x1)[k];
            const float yk0 = ((const float*)&y0)[k];
            const float yk1 = ((const float*)&y1)[k];
            const float uk  = ((const float*)&u)[k];
            const float vk  = ((const float*)&v)[k];
            const float r00 = fmaxf(xk0 + yk0, 0.f);
            const float r01 = fmaxf(xk0 + yk1, 0.f);
            const float r10 = fmaxf(xk1 + yk0, 0.f);
            const float r11 = fmaxf(xk1 + yk1, 0.f);
            acc[0][0][0] = fmaf(r00, uk, acc[0][0][0]);
            acc[0][0][1] = fmaf(r00, vk, acc[0][0][1]);
            acc[0][1][0] = fmaf(r01, uk, acc[0][1][0]);
            acc[0][1][1] = fmaf(r01, vk, acc[0][1][1]);
            acc[1][0][0] = fmaf(r10, uk, acc[1][0][0]);
            acc[1][0][1] = fmaf(r10, vk, acc[1][0][1]);
            acc[1][1][0] = fmaf(r11, uk, acc[1][1][0]);
            acc[1][1][1] = fmaf(r11, vk, acc[1][1][1]);
        }
    }

    #pragma unroll
    for (int ni = 0; ni < 2; ++ni)
        #pragma unroll
        for (int mj = 0; mj < 2; ++mj) {
            const size_t P = ((size_t)(b * 128 + n0 + i0 + ni)) * 128 + (m0 + j0 + mj);
            atomicAdd(&out[P * 2],     acc[ni][mj][0]);
            atomicAdd(&out[P * 2 + 1], acc[ni][mj][1]);
        }
}

extern "C" void kernel_launch(void* const* d_in, const int* in_sizes, int n_in,
                              void* d_out, int out_size, void* d_ws, size_t ws_size,
                              hipStream_t stream) {
    (void)in_sizes; (void)n_in; (void)out_size; (void)ws_size;
    const float* input1 = (const float*)d_in[0];
    const float* input2 = (const float*)d_in[1];
    const float* W1     = (const float*)d_in[2];
    const float* b1     = (const float*)d_in[3];
    const float* W2     = (const float*)d_in[4];
    const float* Wo     = (const float*)d_in[5];
    const float* bo     = (const float*)d_in[6];
    float* out = (float*)d_out;

    ushort* Abig = (ushort*)d_ws;                           // 4.72 MB
    ushort* Wbig = Abig + (size_t)1024 * KP;                // 9.44 MB
    float*  hid  = (float*)(Wbig + (size_t)2 * 1024 * KP);  // 4 MB

    hid_init<<<1024, 256, 0, stream>>>(b1, hid);
    prepack<<<2304, 256, 0, stream>>>(input1, input2, W1, W2, Abig, Wbig);
    gemm_mfma<<<dim3(16, 16, KSPLIT), 256, 0, stream>>>(Abig, Wbig, hid);
    out_init<<<256, 256, 0, stream>>>(bo, out);
    pair_kernel<<<dim3(4, 16, HSPLIT), 256, 0, stream>>>(hid, Wo, out);
}

// Round 6
// 109.216 us; speedup vs baseline: 1.4654x; 1.1833x over previous
//
#include <hip/hip_runtime.h>
#include <hip/hip_bf16.h>

// BiClassifier B=4 N=128 D=768 HID=1024 OUT=2
// k1 prepack:  Abig[1024][2304] bf16 = [hi|lo|hi] of stacked inputs
//              Wbig[2][1024][2304] bf16 = [hi|hi|lo] of W1, W2
// k2 gemm_mfma: hid[1024][1024] = Abig @ Wbig[sel].T + b1(rows<512)
//               in-block split-K x2 (8 waves = 2 K-halves x 4 space), LDS reduce,
//               plain stores — NO atomics.
// k3 pair: out[b,n,m,:] = relu(hid[bn]+hid[512+bm]) @ Wo.T + bo, full h per block,
//          one writer per output — NO atomics.

typedef __attribute__((ext_vector_type(8))) short s16x8;
typedef __attribute__((ext_vector_type(4))) float f32x4;

#define KP 2304
#define BK 64
#define KHALF 1152
#define NSTEP (KHALF / BK)   // 18

__device__ __forceinline__ void gl_lds16(const void* g, void* l) {
    __builtin_amdgcn_global_load_lds(
        (const __attribute__((address_space(1))) unsigned int*)g,
        (__attribute__((address_space(3))) unsigned int*)l, 16, 0, 0);
}

__global__ __launch_bounds__(256) void prepack(
    const float* __restrict__ in1, const float* __restrict__ in2,
    const float* __restrict__ W1, const float* __restrict__ W2,
    ushort* __restrict__ Abig, ushort* __restrict__ Wbig)
{
    const int gid = blockIdx.x * 256 + threadIdx.x;   // 589824 total
    const int src = gid / 196608;                     // 0:A 1:W1 2:W2
    const int rem = gid % 196608;
    const int row = rem / 192;
    const int k4  = (rem % 192) * 4;
    const float* sp;
    ushort* dst;
    if (src == 0) {
        sp  = (row < 512) ? in1 + (size_t)row * 768 + k4
                          : in2 + (size_t)(row - 512) * 768 + k4;
        dst = Abig + (size_t)row * KP + k4;
    } else {
        sp  = (src == 1 ? W1 : W2) + (size_t)row * 768 + k4;
        dst = Wbig + (size_t)(src - 1) * (1024 * KP) + (size_t)row * KP + k4;
    }
    const float4 x = *(const float4*)sp;
    const float xf[4] = {x.x, x.y, x.z, x.w};
    ushort h[4], l[4];
    #pragma unroll
    for (int i = 0; i < 4; ++i) {
        const float v = xf[i];
        __hip_bfloat16 bh = __float2bfloat16(v);
        const float fh = __bfloat162float(bh);
        __hip_bfloat16 bl = __float2bfloat16(v - fh);
        h[i] = *(ushort*)&bh;
        l[i] = *(ushort*)&bl;
    }
    const ushort4 H = make_ushort4(h[0], h[1], h[2], h[3]);
    const ushort4 L = make_ushort4(l[0], l[1], l[2], l[3]);
    if (src == 0) {   // A: [hi | lo | hi]
        *(ushort4*)(dst)        = H;
        *(ushort4*)(dst + 768)  = L;
        *(ushort4*)(dst + 1536) = H;
    } else {          // W: [hi | hi | lo]
        *(ushort4*)(dst)        = H;
        *(ushort4*)(dst + 768)  = H;
        *(ushort4*)(dst + 1536) = L;
    }
}

// 64x64 tile, 512 thr = 8 waves: w>>2 = K-half, w&3 = space wave (2x2 of 32x32).
// Double-buffered global_load_lds staging (swizzle-inverse global src, linear
// LDS dest, XOR-swizzled reads). LDS cross-wave K-reduce epilogue, plain stores.
__global__ __launch_bounds__(512) void gemm_mfma(
    const ushort* __restrict__ Abig, const ushort* __restrict__ Wbig,
    const float* __restrict__ b1, float* __restrict__ hid)
{
    const int t    = threadIdx.x;
    const int lane = t & 63;
    const int w    = t >> 6;
    const int kh   = w >> 2;        // K-half 0/1
    const int ws   = w & 3;         // space wave
    const int row0 = blockIdx.y * 64;
    const int col0 = blockIdx.x * 64;

    const char* __restrict__ A = (const char*)(Abig + (size_t)row0 * KP);
    const char* __restrict__ W = (const char*)(Wbig
                                   + (row0 < 512 ? (size_t)0 : (size_t)1024 * KP)
                                   + (size_t)col0 * KP);

    __shared__ ushort lds[2][2][2][4096];   // [buf][kh][A/W][8KB] = 64KB

    // staging: thread t covers (row = t>>3, k-chunk = t&7) of each 64x64(BK) tile;
    // linear LDS dest (wave w -> bytes [w*1024, w*1024+1KB) of each region),
    // swizzle-inverse global source.
    const int srow = t >> 3;
    const int kbyt = (((t & 7) ^ (srow & 7)) << 4);
    const size_t rowoff = (size_t)srow * (KP * 2);

    // fragment read offsets: phys_byte_in_row = logical ^ ((row&7)<<4)
    const int wr = ws >> 1, wc = ws & 1;
    const int l15 = lane & 15, kg = lane >> 4;
    int aoff[2][2], boff[2][2];   // [kk][frag]
    #pragma unroll
    for (int kk = 0; kk < 2; ++kk)
        #pragma unroll
        for (int f = 0; f < 2; ++f) {
            const int r = wr * 32 + f * 16 + l15;
            const int c = wc * 32 + f * 16 + l15;
            const int sw_ = kk * 64 + kg * 16;
            aoff[kk][f] = r * 128 + (sw_ ^ ((r & 7) << 4));
            boff[kk][f] = c * 128 + (sw_ ^ ((c & 7) << 4));
        }

#define STAGE(buf, ktk) do {                                                   \
        const size_t kby = (size_t)(ktk) * (BK * 2);                           \
        _Pragma("unroll")                                                      \
        for (int p = 0; p < 4; ++p) {                                          \
            const char* src = (p & 1) ? W : A;                                 \
            const size_t off = rowoff + (size_t)(p >> 1) * (KHALF * 2)         \
                               + kby + kbyt;                                   \
            gl_lds16(src + off,                                                \
                     (char*)&lds[buf][p >> 1][p & 1][0] + t * 16);             \
        }                                                                      \
    } while (0)

    const f32x4 zero = {0.f, 0.f, 0.f, 0.f};
    f32x4 acc[2][2] = {{zero, zero}, {zero, zero}};

    STAGE(0, 0);
    int cur = 0;
    for (int kt = 0; kt < NSTEP; ++kt) {
        asm volatile("s_waitcnt vmcnt(0)" ::: "memory");
        __syncthreads();
        if (kt + 1 < NSTEP) STAGE(cur ^ 1, kt + 1);
        const char* __restrict__ ab = (const char*)&lds[cur][kh][0][0];
        const char* __restrict__ wb = (const char*)&lds[cur][kh][1][0];
        #pragma unroll
        for (int kk = 0; kk < 2; ++kk) {
            s16x8 af[2], bf_[2];
            #pragma unroll
            for (int f = 0; f < 2; ++f) {
                af[f]  = *(const s16x8*)(ab + aoff[kk][f]);
                bf_[f] = *(const s16x8*)(wb + boff[kk][f]);
            }
            #pragma unroll
            for (int fr = 0; fr < 2; ++fr)
                #pragma unroll
                for (int fc = 0; fc < 2; ++fc)
                    acc[fr][fc] = __builtin_amdgcn_mfma_f32_16x16x32_bf16(
                        af[fr], bf_[fc], acc[fr][fc], 0, 0, 0);
        }
        cur ^= 1;
    }
#undef STAGE

    // cross-wave K-reduce: kh==1 waves park accs in LDS, kh==0 waves fold+store.
    __syncthreads();
    float* red = (float*)&lds[0][0][0][0];   // 64KB scratch, reuse staging LDS
    if (kh == 1) {
        #pragma unroll
        for (int fr = 0; fr < 2; ++fr)
            #pragma unroll
            for (int fc = 0; fc < 2; ++fc)
                *(f32x4*)&red[(((ws * 2 + fr) * 2 + fc) * 64 + lane) * 4] =
                    acc[fr][fc];
    }
    __syncthreads();
    if (kh == 0) {
        float bias[2] = {0.f, 0.f};
        if (row0 < 512) {
            bias[0] = b1[col0 + wc * 32 + l15];
            bias[1] = b1[col0 + wc * 32 + 16 + l15];
        }
        #pragma unroll
        for (int fr = 0; fr < 2; ++fr)
            #pragma unroll
            for (int fc = 0; fc < 2; ++fc) {
                const f32x4 o = *(const f32x4*)
                    &red[(((ws * 2 + fr) * 2 + fc) * 64 + lane) * 4];
                #pragma unroll
                for (int i = 0; i < 4; ++i) {
                    const int r = row0 + wr * 32 + fr * 16 + kg * 4 + i;
                    const int c = col0 + wc * 32 + fc * 16 + l15;
                    hid[(size_t)r * 1024 + c] = acc[fr][fc][i] + o[i] + bias[fc];
                }
            }
    }
}

// 16x16 pair tile, full h = 1024 in 8 double-buffered chunks of 128.
// Wo fully LDS-resident. Each thread owns one pair -> direct float2 store + bo.
__global__ __launch_bounds__(256) void pair_kernel(
    const float* __restrict__ hid, const float* __restrict__ Wo,
    const float* __restrict__ bo, float* __restrict__ out)
{
    const int t  = threadIdx.x;
    const int b  = blockIdx.z;
    const int n0 = blockIdx.y * 16;
    const int m0 = blockIdx.x * 16;

    __shared__ float s1[2][16][132];
    __shared__ float s2[2][16][132];
    __shared__ float sw[2][1024];

    // stage all of Wo once (2048 floats = 512 float4 / 256 thr)
    #pragma unroll
    for (int q = 0; q < 2; ++q) {
        const int fi = q * 256 + t;
        ((float4*)sw)[fi] = ((const float4*)Wo)[fi];
    }

    // chunk staging map: idx = p*256+t -> row = idx>>5, col4 = (idx&31)*4
    const int rr0 = t >> 5;            // p=0 row
    const int cc  = (t & 31) << 2;
    const float* __restrict__ base1 = hid + ((size_t)(b * 128 + n0)) * 1024;
    const float* __restrict__ base2 = hid + ((size_t)(512 + b * 128 + m0)) * 1024;

    float4 a0 = *(const float4*)&base1[(size_t)rr0 * 1024 + cc];
    float4 a1 = *(const float4*)&base1[(size_t)(rr0 + 8) * 1024 + cc];
    float4 c0 = *(const float4*)&base2[(size_t)rr0 * 1024 + cc];
    float4 c1 = *(const float4*)&base2[(size_t)(rr0 + 8) * 1024 + cc];

    const int i = t >> 4, j = t & 15;
    float acc0 = 0.f, acc1 = 0.f;
    int cur = 0;

    for (int hc = 0; hc < 8; ++hc) {
        *(float4*)&s1[cur][rr0][cc]     = a0;
        *(float4*)&s1[cur][rr0 + 8][cc] = a1;
        *(float4*)&s2[cur][rr0][cc]     = c0;
        *(float4*)&s2[cur][rr0 + 8][cc] = c1;
        __syncthreads();
        if (hc < 7) {
            const int off = (hc + 1) * 128 + cc;
            a0 = *(const float4*)&base1[(size_t)rr0 * 1024 + off];
            a1 = *(const float4*)&base1[(size_t)(rr0 + 8) * 1024 + off];
            c0 = *(const float4*)&base2[(size_t)rr0 * 1024 + off];
            c1 = *(const float4*)&base2[(size_t)(rr0 + 8) * 1024 + off];
        }
        const float* __restrict__ xrow = &s1[cur][i][0];
        const float* __restrict__ yrow = &s2[cur][j][0];
        const float* __restrict__ u = &sw[0][hc * 128];
        const float* __restrict__ v = &sw[1][hc * 128];
        #pragma unroll
        for (int c4 = 0; c4 < 32; ++c4) {
            const float4 x = *(const float4*)&xrow[c4 * 4];
            const float4 y = *(const float4*)&yrow[c4 * 4];
            const float4 uu = *(const float4*)&u[c4 * 4];
            const float4 vv = *(const float4*)&v[c4 * 4];
            float r;
            r = fmaxf(x.x + y.x, 0.f); acc0 = fmaf(r, uu.x, acc0); acc1 = fmaf(r, vv.x, acc1);
            r = fmaxf(x.y + y.y, 0.f); acc0 = fmaf(r, uu.y, acc0); acc1 = fmaf(r, vv.y, acc1);
            r = fmaxf(x.z + y.z, 0.f); acc0 = fmaf(r, uu.z, acc0); acc1 = fmaf(r, vv.z, acc1);
            r = fmaxf(x.w + y.w, 0.f); acc0 = fmaf(r, uu.w, acc0); acc1 = fmaf(r, vv.w, acc1);
        }
        __syncthreads();
        cur ^= 1;
    }

    const float2 ob = *(const float2*)bo;
    const size_t P = (((size_t)b * 128 + n0 + i) * 128 + (m0 + j)) * 2;
    *(float2*)&out[P] = make_float2(acc0 + ob.x, acc1 + ob.y);
}

extern "C" void kernel_launch(void* const* d_in, const int* in_sizes, int n_in,
                              void* d_out, int out_size, void* d_ws, size_t ws_size,
                              hipStream_t stream) {
    (void)in_sizes; (void)n_in; (void)out_size; (void)ws_size;
    const float* input1 = (const float*)d_in[0];
    const float* input2 = (const float*)d_in[1];
    const float* W1     = (const float*)d_in[2];
    const float* b1     = (const float*)d_in[3];
    const float* W2     = (const float*)d_in[4];
    const float* Wo     = (const float*)d_in[5];
    const float* bo     = (const float*)d_in[6];
    float* out = (float*)d_out;

    ushort* Abig = (ushort*)d_ws;                           // 4.72 MB
    ushort* Wbig = Abig + (size_t)1024 * KP;                // 9.44 MB
    float*  hid  = (float*)(Wbig + (size_t)2 * 1024 * KP);  // 4 MB

    prepack<<<2304, 256, 0, stream>>>(input1, input2, W1, W2, Abig, Wbig);
    gemm_mfma<<<dim3(16, 16), 512, 0, stream>>>(Abig, Wbig, b1, hid);
    pair_kernel<<<dim3(8, 8, 4), 256, 0, stream>>>(hid, Wo, bo, out);
}

// Round 7
// 105.862 us; speedup vs baseline: 1.5119x; 1.0317x over previous
//
#include <hip/hip_runtime.h>
#include <hip/hip_bf16.h>

// BiClassifier B=4 N=128 D=768 HID=1024 OUT=2
// k1 prepack:  Abig[1024][2304] bf16 = [hi|lo|hi] of stacked inputs
//              Wbig[2][1024][2304] bf16 = [hi|hi|lo] of W1, W2     [R6-proven]
// k2 gemm_mfma: hid = Abig @ Wbig[sel].T + b1, in-block split-K x2  [R6-proven]
// k3 out_init: out[p][:] = bo                                       [R5-proven]
// k4 pair: 16x16 pair tile x h-range 256 (grid 1024 = 4 blocks/CU),
//          atomicAdd partials onto bo-initialized out               [R5-proven pattern]

typedef __attribute__((ext_vector_type(8))) short s16x8;
typedef __attribute__((ext_vector_type(4))) float f32x4;

#define KP 2304
#define BK 64
#define KHALF 1152
#define NSTEP (KHALF / BK)   // 18

__device__ __forceinline__ void gl_lds16(const void* g, void* l) {
    __builtin_amdgcn_global_load_lds(
        (const __attribute__((address_space(1))) unsigned int*)g,
        (__attribute__((address_space(3))) unsigned int*)l, 16, 0, 0);
}

__global__ __launch_bounds__(256) void prepack(
    const float* __restrict__ in1, const float* __restrict__ in2,
    const float* __restrict__ W1, const float* __restrict__ W2,
    ushort* __restrict__ Abig, ushort* __restrict__ Wbig)
{
    const int gid = blockIdx.x * 256 + threadIdx.x;   // 589824 total
    const int src = gid / 196608;                     // 0:A 1:W1 2:W2
    const int rem = gid % 196608;
    const int row = rem / 192;
    const int k4  = (rem % 192) * 4;
    const float* sp;
    ushort* dst;
    if (src == 0) {
        sp  = (row < 512) ? in1 + (size_t)row * 768 + k4
                          : in2 + (size_t)(row - 512) * 768 + k4;
        dst = Abig + (size_t)row * KP + k4;
    } else {
        sp  = (src == 1 ? W1 : W2) + (size_t)row * 768 + k4;
        dst = Wbig + (size_t)(src - 1) * (1024 * KP) + (size_t)row * KP + k4;
    }
    const float4 x = *(const float4*)sp;
    const float xf[4] = {x.x, x.y, x.z, x.w};
    ushort h[4], l[4];
    #pragma unroll
    for (int i = 0; i < 4; ++i) {
        const float v = xf[i];
        __hip_bfloat16 bh = __float2bfloat16(v);
        const float fh = __bfloat162float(bh);
        __hip_bfloat16 bl = __float2bfloat16(v - fh);
        h[i] = *(ushort*)&bh;
        l[i] = *(ushort*)&bl;
    }
    const ushort4 H = make_ushort4(h[0], h[1], h[2], h[3]);
    const ushort4 L = make_ushort4(l[0], l[1], l[2], l[3]);
    if (src == 0) {   // A: [hi | lo | hi]
        *(ushort4*)(dst)        = H;
        *(ushort4*)(dst + 768)  = L;
        *(ushort4*)(dst + 1536) = H;
    } else {          // W: [hi | hi | lo]
        *(ushort4*)(dst)        = H;
        *(ushort4*)(dst + 768)  = H;
        *(ushort4*)(dst + 1536) = L;
    }
}

// 64x64 tile, 512 thr = 8 waves: w>>2 = K-half, w&3 = space wave (2x2 of 32x32).
__global__ __launch_bounds__(512) void gemm_mfma(
    const ushort* __restrict__ Abig, const ushort* __restrict__ Wbig,
    const float* __restrict__ b1, float* __restrict__ hid)
{
    const int t    = threadIdx.x;
    const int lane = t & 63;
    const int w    = t >> 6;
    const int kh   = w >> 2;        // K-half 0/1
    const int ws   = w & 3;         // space wave
    const int row0 = blockIdx.y * 64;
    const int col0 = blockIdx.x * 64;

    const char* __restrict__ A = (const char*)(Abig + (size_t)row0 * KP);
    const char* __restrict__ W = (const char*)(Wbig
                                   + (row0 < 512 ? (size_t)0 : (size_t)1024 * KP)
                                   + (size_t)col0 * KP);

    __shared__ ushort lds[2][2][2][4096];   // [buf][kh][A/W][8KB] = 64KB

    const int srow = t >> 3;
    const int kbyt = (((t & 7) ^ (srow & 7)) << 4);
    const size_t rowoff = (size_t)srow * (KP * 2);

    const int wr = ws >> 1, wc = ws & 1;
    const int l15 = lane & 15, kg = lane >> 4;
    int aoff[2][2], boff[2][2];   // [kk][frag]
    #pragma unroll
    for (int kk = 0; kk < 2; ++kk)
        #pragma unroll
        for (int f = 0; f < 2; ++f) {
            const int r = wr * 32 + f * 16 + l15;
            const int c = wc * 32 + f * 16 + l15;
            const int sw_ = kk * 64 + kg * 16;
            aoff[kk][f] = r * 128 + (sw_ ^ ((r & 7) << 4));
            boff[kk][f] = c * 128 + (sw_ ^ ((c & 7) << 4));
        }

#define STAGE(buf, ktk) do {                                                   \
        const size_t kby = (size_t)(ktk) * (BK * 2);                           \
        _Pragma("unroll")                                                      \
        for (int p = 0; p < 4; ++p) {                                          \
            const char* src = (p & 1) ? W : A;                                 \
            const size_t off = rowoff + (size_t)(p >> 1) * (KHALF * 2)         \
                               + kby + kbyt;                                   \
            gl_lds16(src + off,                                                \
                     (char*)&lds[buf][p >> 1][p & 1][0] + t * 16);             \
        }                                                                      \
    } while (0)

    const f32x4 zero = {0.f, 0.f, 0.f, 0.f};
    f32x4 acc[2][2] = {{zero, zero}, {zero, zero}};

    STAGE(0, 0);
    int cur = 0;
    for (int kt = 0; kt < NSTEP; ++kt) {
        asm volatile("s_waitcnt vmcnt(0)" ::: "memory");
        __syncthreads();
        if (kt + 1 < NSTEP) STAGE(cur ^ 1, kt + 1);
        const char* __restrict__ ab = (const char*)&lds[cur][kh][0][0];
        const char* __restrict__ wb = (const char*)&lds[cur][kh][1][0];
        #pragma unroll
        for (int kk = 0; kk < 2; ++kk) {
            s16x8 af[2], bf_[2];
            #pragma unroll
            for (int f = 0; f < 2; ++f) {
                af[f]  = *(const s16x8*)(ab + aoff[kk][f]);
                bf_[f] = *(const s16x8*)(wb + boff[kk][f]);
            }
            #pragma unroll
            for (int fr = 0; fr < 2; ++fr)
                #pragma unroll
                for (int fc = 0; fc < 2; ++fc)
                    acc[fr][fc] = __builtin_amdgcn_mfma_f32_16x16x32_bf16(
                        af[fr], bf_[fc], acc[fr][fc], 0, 0, 0);
        }
        cur ^= 1;
    }
#undef STAGE

    __syncthreads();
    float* red = (float*)&lds[0][0][0][0];
    if (kh == 1) {
        #pragma unroll
        for (int fr = 0; fr < 2; ++fr)
            #pragma unroll
            for (int fc = 0; fc < 2; ++fc)
                *(f32x4*)&red[(((ws * 2 + fr) * 2 + fc) * 64 + lane) * 4] =
                    acc[fr][fc];
    }
    __syncthreads();
    if (kh == 0) {
        float bias[2] = {0.f, 0.f};
        if (row0 < 512) {
            bias[0] = b1[col0 + wc * 32 + l15];
            bias[1] = b1[col0 + wc * 32 + 16 + l15];
        }
        #pragma unroll
        for (int fr = 0; fr < 2; ++fr)
            #pragma unroll
            for (int fc = 0; fc < 2; ++fc) {
                const f32x4 o = *(const f32x4*)
                    &red[(((ws * 2 + fr) * 2 + fc) * 64 + lane) * 4];
                #pragma unroll
                for (int i = 0; i < 4; ++i) {
                    const int r = row0 + wr * 32 + fr * 16 + kg * 4 + i;
                    const int c = col0 + wc * 32 + fc * 16 + l15;
                    hid[(size_t)r * 1024 + c] = acc[fr][fc][i] + o[i] + bias[fc];
                }
            }
    }
}

__global__ __launch_bounds__(256) void out_init(
    const float* __restrict__ bo, float* __restrict__ out)
{
    const int g = blockIdx.x * 256 + threadIdx.x;   // 65536 pairs
    *(float2*)&out[(size_t)g * 2] = make_float2(bo[0], bo[1]);
}

// 16x16 pair tile x h-range 256. Grid (8,8,16): z = b*4 + h-split.
// 1024 blocks = 4 blocks/CU = 4 waves/SIMD. Single-shot LDS staging, one
// barrier, then 64 h4-iterations; atomicAdd partials onto bo-initialized out.
__global__ __launch_bounds__(256) void pair_kernel(
    const float* __restrict__ hid, const float* __restrict__ Wo,
    float* __restrict__ out)
{
    const int t  = threadIdx.x;
    const int b  = blockIdx.z >> 2;
    const int h0 = (blockIdx.z & 3) * 256;
    const int n0 = blockIdx.y * 16;
    const int m0 = blockIdx.x * 16;

    __shared__ float s1[16][260];   // stride 260: rows j, j+8 alias 2-way (free)
    __shared__ float s2[16][260];
    __shared__ float sw[2][256];

    const float* __restrict__ base1 = hid + ((size_t)(b * 128 + n0)) * 1024 + h0;
    const float* __restrict__ base2 = hid + ((size_t)(512 + b * 128 + m0)) * 1024 + h0;

    // stage 16 rows x 256 floats per tensor: slot = p*256+t; row = slot>>6, c4 = slot&63
    #pragma unroll
    for (int p = 0; p < 4; ++p) {
        const int slot = p * 256 + t;
        const int r  = slot >> 6;
        const int c  = (slot & 63) << 2;
        *(float4*)&s1[r][c] = *(const float4*)&base1[(size_t)r * 1024 + c];
        *(float4*)&s2[r][c] = *(const float4*)&base2[(size_t)r * 1024 + c];
    }
    if (t < 128) {
        const int o = t >> 6;
        const int c = (t & 63) << 2;
        *(float4*)&sw[o][c] = *(const float4*)&Wo[(size_t)o * 1024 + h0 + c];
    }
    __syncthreads();

    const int i = t >> 4, j = t & 15;
    const float* __restrict__ xrow = &s1[i][0];
    const float* __restrict__ yrow = &s2[j][0];
    float acc0 = 0.f, acc1 = 0.f;

    #pragma unroll 8
    for (int c4 = 0; c4 < 64; ++c4) {
        const float4 x  = *(const float4*)&xrow[c4 * 4];
        const float4 y  = *(const float4*)&yrow[c4 * 4];
        const float4 uu = *(const float4*)&sw[0][c4 * 4];
        const float4 vv = *(const float4*)&sw[1][c4 * 4];
        float r;
        r = fmaxf(x.x + y.x, 0.f); acc0 = fmaf(r, uu.x, acc0); acc1 = fmaf(r, vv.x, acc1);
        r = fmaxf(x.y + y.y, 0.f); acc0 = fmaf(r, uu.y, acc0); acc1 = fmaf(r, vv.y, acc1);
        r = fmaxf(x.z + y.z, 0.f); acc0 = fmaf(r, uu.z, acc0); acc1 = fmaf(r, vv.z, acc1);
        r = fmaxf(x.w + y.w, 0.f); acc0 = fmaf(r, uu.w, acc0); acc1 = fmaf(r, vv.w, acc1);
    }

    const size_t P = (((size_t)b * 128 + n0 + i) * 128 + (m0 + j)) * 2;
    atomicAdd(&out[P],     acc0);
    atomicAdd(&out[P + 1], acc1);
}

extern "C" void kernel_launch(void* const* d_in, const int* in_sizes, int n_in,
                              void* d_out, int out_size, void* d_ws, size_t ws_size,
                              hipStream_t stream) {
    (void)in_sizes; (void)n_in; (void)out_size; (void)ws_size;
    const float* input1 = (const float*)d_in[0];
    const float* input2 = (const float*)d_in[1];
    const float* W1     = (const float*)d_in[2];
    const float* b1     = (const float*)d_in[3];
    const float* W2     = (const float*)d_in[4];
    const float* Wo     = (const float*)d_in[5];
    const float* bo     = (const float*)d_in[6];
    float* out = (float*)d_out;

    ushort* Abig = (ushort*)d_ws;                           // 4.72 MB
    ushort* Wbig = Abig + (size_t)1024 * KP;                // 9.44 MB
    float*  hid  = (float*)(Wbig + (size_t)2 * 1024 * KP);  // 4 MB

    prepack<<<2304, 256, 0, stream>>>(input1, input2, W1, W2, Abig, Wbig);
    gemm_mfma<<<dim3(16, 16), 512, 0, stream>>>(Abig, Wbig, b1, hid);
    out_init<<<256, 256, 0, stream>>>(bo, out);
    pair_kernel<<<dim3(8, 8, 16), 256, 0, stream>>>(hid, Wo, out);
}